// Round 6
// baseline (178.742 us; speedup 1.0000x reference)
//
#include <hip/hip_runtime.h>

// Hough voting (PoseCNN-style), two-phase binned version, round 6.
// label (B,H,W) i32; vertex (B,3C,H,W) f32; extents (C,3); meta (B,9);
// out (B,C,9) f32. B=2,C=22,H=480,W=640. Assumes H <= 512, C < 32.
//
// r6 change: r4/r5 showed all pipes <25% busy with occupancy parked at 38% --
// barrier/phase serialization across 8-wave blocks, only 4 blocks/CU. This
// round: 256-thread/256-px blocks (LDS 22KB -> 7 blocks/CU, 4-wave barrier
// scope, 2400 blocks), votes recomputed in pass B to keep VGPR<=64 (8
// waves/SIMD). Scan covers 480 row-bins at 2 bins/thread.

#define MAXC 32

__global__ __launch_bounds__(256) void emit_kernel(
    const int* __restrict__ label, const float* __restrict__ vertex,
    unsigned short* __restrict__ bucketData, unsigned* __restrict__ cursor,
    unsigned* __restrict__ cnt, float* __restrict__ zsum,
    int C, int H, int W, int HW, int CAP)
{
    __shared__ unsigned s_bin[512];         // votes per destination row
    __shared__ unsigned s_pos[512];         // excl base -> (after pass B) incl end
    __shared__ unsigned s_gbase[512];       // global base per row
    __shared__ unsigned short s_buf[8192];  // binned records, grouped by row
    __shared__ unsigned s_wtot[4];
    __shared__ unsigned s_ccnt[MAXC];
    __shared__ float s_cz[MAXC];

    int tid = threadIdx.x;
    int lane = tid & 63, wave = tid >> 6;
    int b = blockIdx.y;
    int p = blockIdx.x * 256 + tid;

    s_bin[tid] = 0;
    s_bin[tid + 256] = 0;
    if (tid < MAXC) { s_ccnt[tid] = 0u; s_cz[tid] = 0.0f; }
    __syncthreads();

    int lab = 0;
    bool fg = false;
    float nxn = 0.f, nyn = 0.f, xs = 0.f, ys = 0.f;
    if (p < HW) {
        lab = label[(size_t)b * HW + p];
        // Coalesced full-plane sweep (L3-resident) + select; avoids the
        // scattered label-directed gather.
        const float* vbase = vertex + (size_t)b * 3 * C * HW + p;
        float nx = 0.f, ny = 0.f, z = 0.f;
        #pragma unroll 2
        for (int c = 0; c < C; ++c) {
            float v0 = vbase[(size_t)(3 * c + 0) * HW];
            float v1 = vbase[(size_t)(3 * c + 1) * HW];
            float v2 = vbase[(size_t)(3 * c + 2) * HW];
            if (lab == c) { nx = v0; ny = v1; z = v2; }
        }
        atomicAdd(&s_ccnt[lab], 1u);
        atomicAdd(&s_cz[lab], z);
        if (lab > 0) {
            fg = true;
            // Match XLA f32 exactly: no FMA contraction, IEEE sqrt/div, RNE round.
            float nrm = __fsqrt_rn(__fadd_rn(__fmul_rn(nx, nx), __fmul_rn(ny, ny)));
            float inv = __fdiv_rn(1.0f, __fadd_rn(nrm, 1e-8f));
            nxn = __fmul_rn(nx, inv);
            nyn = __fmul_rn(ny, inv);
            xs = (float)(p % W);
            ys = (float)(p / W);
        }
    }

    // Pass A: count votes per destination row (recomputed again in pass B;
    // identical rounding sequence -> identical px/py both times).
    if (fg) {
        #pragma unroll
        for (int i = 1; i <= 32; ++i) {
            float t = (float)i * 4.0f;
            int px = (int)rintf(__fadd_rn(xs, __fmul_rn(nxn, t)));
            int py = (int)rintf(__fadd_rn(ys, __fmul_rn(nyn, t)));
            if (px >= 0 && px < W && py >= 0 && py < H)
                atomicAdd(&s_bin[py], 1u);
        }
    }
    __syncthreads();

    // Inclusive scan over 512 bins, 2 bins per thread (pair-sum shuffle scan).
    unsigned b0 = s_bin[2 * tid], b1 = s_bin[2 * tid + 1];
    unsigned pairsum = b0 + b1;
    unsigned v = pairsum;
    #pragma unroll
    for (int off = 1; off < 64; off <<= 1) {
        unsigned u = __shfl_up(v, off, 64);
        if (lane >= off) v += u;
    }
    if (lane == 63) s_wtot[wave] = v;
    __syncthreads();
    if (tid == 0) {
        unsigned a = 0;
        #pragma unroll
        for (int w2 = 0; w2 < 4; ++w2) { unsigned t2 = s_wtot[w2]; s_wtot[w2] = a; a += t2; }
    }
    __syncthreads();
    unsigned ebase0 = v + s_wtot[wave] - pairsum;  // exclusive base of bin 2*tid
    s_pos[2 * tid]     = ebase0;
    s_pos[2 * tid + 1] = ebase0 + b0;

    // Reserve global space for rows 2t, 2t+1 (independent atomics, latency
    // hides under pass B).
    int y0 = 2 * tid, y1 = 2 * tid + 1;
    unsigned g0 = 0, g1 = 0;
    if (y0 < H && b0) g0 = atomicAdd(&cursor[b * H + y0], b0);
    if (y1 < H && b1) g1 = atomicAdd(&cursor[b * H + y1], b1);
    s_gbase[y0] = g0;
    s_gbase[y1] = g1;
    __syncthreads();

    // Pass B: scatter records into row-grouped LDS buffer.
    if (fg) {
        #pragma unroll
        for (int i = 1; i <= 32; ++i) {
            float t = (float)i * 4.0f;
            int px = (int)rintf(__fadd_rn(xs, __fmul_rn(nxn, t)));
            int py = (int)rintf(__fadd_rn(ys, __fmul_rn(nyn, t)));
            if (px >= 0 && px < W && py >= 0 && py < H) {
                unsigned slot = atomicAdd(&s_pos[py], 1u);
                s_buf[slot] = (unsigned short)(((unsigned)lab << 10) | (unsigned)px);
            }
        }
    }
    __syncthreads();
    // s_pos[y] is now the INCLUSIVE scan (base + n).

    // Coalesced copy-out: wave w handles rows w, w+4, ...
    for (int y = wave; y < H; y += 4) {
        unsigned n = s_bin[y];
        if (!n) continue;
        unsigned eb = s_pos[y] - n;
        unsigned gb = s_gbase[y];
        unsigned short* dst = bucketData + (size_t)(b * H + y) * CAP;
        for (unsigned i = (unsigned)lane; i < n; i += 64) {
            unsigned g = gb + i;
            if (g < (unsigned)CAP) dst[g] = s_buf[eb + i];
        }
    }

    // Class aggregates (s_ccnt/s_cz final since the first barrier after load).
    if (tid < C) {
        unsigned c = s_ccnt[tid];
        if (c) {
            atomicAdd(&cnt[b * C + tid], c);
            atomicAdd(&zsum[b * C + tid], s_cz[tid]);
        }
    }
}

__global__ __launch_bounds__(256) void hist_kernel(
    const unsigned short* __restrict__ bucketData,
    const unsigned* __restrict__ cursor,
    unsigned long long* __restrict__ keys,
    int C, int H, int W, int CAP)
{
    extern __shared__ char sm[];
    unsigned* hist = (unsigned*)sm;   // C*W/2 words, u16 pair per word
    unsigned long long* s_wb =
        (unsigned long long*)(sm + (size_t)(C * W / 2) * 4);  // C*4 wave bests

    int tid = threadIdx.x;
    int lane = tid & 63, wave = tid >> 6;
    int py = blockIdx.x;
    int b = blockIdx.y;
    int words = C * W / 2;

    for (int i = tid; i < words; i += 256) hist[i] = 0u;
    __syncthreads();

    int bucket = b * H + py;
    unsigned n = cursor[bucket];
    if (n > (unsigned)CAP) n = (unsigned)CAP;
    const unsigned short* src = bucketData + (size_t)bucket * CAP;
    for (unsigned i = tid; i < n; i += 256) {
        unsigned r = src[i];
        unsigned idx = (r >> 10) * (unsigned)W + (r & 1023u);  // c*W+px
        atomicAdd(&hist[idx >> 1], 1u << ((idx & 1u) * 16));   // packed u16; max <= CAP < 65536
    }
    __syncthreads();

    // Per-class argmax over ALL cells of this row (zero counts included so
    // global tie-break == jnp.argmax: max count, then min flat index).
    unsigned rowbase = (unsigned)py * (unsigned)W;
    for (int c = 0; c < C; ++c) {
        unsigned long long best = 0;
        for (int px = tid; px < W; px += 256) {
            unsigned cv = (hist[(unsigned)(c * W + px) >> 1] >> ((px & 1) * 16)) & 0xFFFFu;
            unsigned long long k = ((unsigned long long)cv << 32)
                                 | (unsigned long long)(0xFFFFFFFFu - (rowbase + px));
            if (k > best) best = k;
        }
        #pragma unroll
        for (int off = 32; off > 0; off >>= 1) {
            unsigned long long o = __shfl_xor(best, off, 64);
            if (o > best) best = o;
        }
        if (lane == 0) s_wb[c * 4 + wave] = best;
    }
    __syncthreads();
    if (tid < C) {
        unsigned long long m = s_wb[tid * 4];
        #pragma unroll
        for (int w2 = 1; w2 < 4; ++w2)
            if (s_wb[tid * 4 + w2] > m) m = s_wb[tid * 4 + w2];
        atomicMax(&keys[b * C + tid], m);
    }
}

__global__ void finalize_kernel(const unsigned long long* __restrict__ keys,
                                const unsigned* __restrict__ cnt,
                                const float* __restrict__ zsum,
                                const float* __restrict__ extents,
                                const float* __restrict__ meta,
                                float* __restrict__ out,
                                int B, int C, int W)
{
    int i = threadIdx.x;
    if (i >= B * C) return;
    int b = i / C, c = i % C;
    unsigned long long k = keys[i];
    unsigned votes = (unsigned)(k >> 32);
    unsigned peak = 0xFFFFFFFFu - (unsigned)(k & 0xFFFFFFFFull);
    float cx = (float)(peak % (unsigned)W);
    float cy = (float)(peak / (unsigned)W);
    float n = (float)cnt[i];
    float depth = zsum[i] / fmaxf(n, 1.0f);
    float fx = meta[b * 9 + 0];
    const float* e = extents + c * 3;
    float diag = sqrtf(e[0] * e[0] + e[1] * e[1] + e[2] * e[2]);
    float half = 0.5f * diag * fx / fmaxf(fabsf(depth), 0.001f);
    float* o = out + (size_t)i * 9;
    o[0] = (float)c;
    o[1] = (float)votes;
    o[2] = cx - half;
    o[3] = cy - half;
    o[4] = cx + half;
    o[5] = cy + half;
    o[6] = cx;
    o[7] = cy;
    o[8] = depth;
}

extern "C" void kernel_launch(void* const* d_in, const int* in_sizes, int n_in,
                              void* d_out, int out_size, void* d_ws, size_t ws_size,
                              hipStream_t stream)
{
    const int* label    = (const int*)d_in[0];
    const float* vertex = (const float*)d_in[1];
    const float* extents= (const float*)d_in[2];
    const float* meta   = (const float*)d_in[3];
    // d_in[4] = gt (unused), d_in[5] = is_train (unused)

    int C = in_sizes[2] / 3;      // extents: C*3
    int B = in_sizes[3] / 9;      // meta: B*9
    int HW = in_sizes[0] / B;     // label: B*H*W
    const int W = 640;
    int H = HW / W;
    int NB = B * H;               // number of row buckets

    // Workspace layout: keys (u64) | cursor (u32) | cnt | zsum | pad | bucketData (u16)
    size_t keysOff = 0;
    size_t curOff  = keysOff + (size_t)B * C * 8;
    size_t cntOff  = curOff + (size_t)NB * 4;
    size_t zsumOff = cntOff + (size_t)B * C * 4;
    size_t zeroEnd = zsumOff + (size_t)B * C * 4;
    size_t dataOff = (zeroEnd + 63) & ~(size_t)63;

    // Adaptive bucket capacity (records are u16). Mean load ~20K/bucket.
    size_t availRec = (ws_size > dataOff) ? (ws_size - dataOff) / ((size_t)NB * 2) : 0;
    int CAP = (int)(availRec > 32768 ? 32768 : availRec);
    CAP &= ~63;

    unsigned long long* keys = (unsigned long long*)((char*)d_ws + keysOff);
    unsigned* cursor         = (unsigned*)((char*)d_ws + curOff);
    unsigned* cnt            = (unsigned*)((char*)d_ws + cntOff);
    float* zsum              = (float*)((char*)d_ws + zsumOff);
    unsigned short* bucketData = (unsigned short*)((char*)d_ws + dataOff);

    hipMemsetAsync(d_ws, 0, zeroEnd, stream);

    dim3 egrid((HW + 255) / 256, B);
    emit_kernel<<<egrid, 256, 0, stream>>>(label, vertex, bucketData, cursor,
                                           cnt, zsum, C, H, W, HW, CAP);

    dim3 hgrid(H, B);
    size_t hsm = (size_t)(C * W / 2) * 4 + (size_t)C * 4 * 8;
    hist_kernel<<<hgrid, 256, hsm, stream>>>(bucketData, cursor, keys, C, H, W, CAP);

    finalize_kernel<<<1, 64, 0, stream>>>(keys, cnt, zsum, extents, meta,
                                          (float*)d_out, B, C, W);
}

// Round 7
// 128.666 us; speedup vs baseline: 1.3892x; 1.3892x over previous
//
#include <hip/hip_runtime.h>

// Hough voting (PoseCNN-style), two-phase binned version, round 7.
// label (B,H,W) i32; vertex (B,3C,H,W) f32; extents (C,3); meta (B,9);
// out (B,C,9) f32. B=2,C=22,H=480,W=640. Assumes H <= 512, C < 32.
//
// r7 change: r6 showed occupancy was not the parked resource; r4's cost was
// the LDS store-and-regroup (s_buf scatter + scan + serial copy-out + 39KB
// LDS + 6 barriers). Delete all of it: pass A counts votes/row, one parallel
// cursor atomic per row reserves the global range, pass B writes each vote
// DIRECTLY to its row bucket at gbase[py] + rel[py]++ (plain u16 stores;
// per-(block,row) destinations are consecutive, L2 write-allocate merges
// them -- unlike r2's device-scope atomics). LDS 39KB -> 6.5KB, 3 barriers.

#define MAXC 32

__global__ __launch_bounds__(512) void emit_kernel(
    const int* __restrict__ label, const float* __restrict__ vertex,
    unsigned short* __restrict__ bucketData, unsigned* __restrict__ cursor,
    unsigned* __restrict__ cnt, float* __restrict__ zsum,
    int C, int H, int W, int HW, int CAP)
{
    __shared__ unsigned s_bin[512];   // votes per destination row
    __shared__ unsigned s_rel[512];   // block-local write offset per row
    __shared__ unsigned s_gb[512];    // global base per row
    __shared__ unsigned s_ccnt[MAXC];
    __shared__ float s_cz[MAXC];

    int tid = threadIdx.x;
    int b = blockIdx.y;
    int p = blockIdx.x * 512 + tid;

    s_bin[tid] = 0u;
    s_rel[tid] = 0u;
    if (tid < MAXC) { s_ccnt[tid] = 0u; s_cz[tid] = 0.0f; }
    __syncthreads();

    int lab = 0;
    unsigned vote[32];   // py<<10 | px, 0xFFFFFFFF = invalid (static idx only)
    bool fg = false;
    if (p < HW) {
        lab = label[(size_t)b * HW + p];
        const float* vb = vertex + ((size_t)(b * 3 * C + 3 * lab)) * HW + p;
        float nx = vb[0];
        float ny = vb[(size_t)HW];
        float z  = vb[2 * (size_t)HW];
        atomicAdd(&s_ccnt[lab], 1u);
        atomicAdd(&s_cz[lab], z);
        if (lab > 0) {
            fg = true;
            // Match XLA f32 exactly: no FMA contraction, IEEE sqrt/div, RNE round.
            float nrm = __fsqrt_rn(__fadd_rn(__fmul_rn(nx, nx), __fmul_rn(ny, ny)));
            float inv = __fdiv_rn(1.0f, __fadd_rn(nrm, 1e-8f));
            float nxn = __fmul_rn(nx, inv);
            float nyn = __fmul_rn(ny, inv);
            float xs = (float)(p % W);
            float ys = (float)(p / W);
            #pragma unroll
            for (int i = 1; i <= 32; ++i) {
                float t = (float)i * 4.0f;
                int px = (int)rintf(__fadd_rn(xs, __fmul_rn(nxn, t)));
                int py = (int)rintf(__fadd_rn(ys, __fmul_rn(nyn, t)));
                vote[i - 1] = (px >= 0 && px < W && py >= 0 && py < H)
                            ? ((unsigned)(py << 10) | (unsigned)px) : 0xFFFFFFFFu;
            }
        }
    }
    if (!fg) {
        #pragma unroll
        for (int i = 0; i < 32; ++i) vote[i] = 0xFFFFFFFFu;
    }

    // Pass A: count votes per destination row.
    #pragma unroll
    for (int i = 0; i < 32; ++i)
        if (vote[i] != 0xFFFFFFFFu) atomicAdd(&s_bin[vote[i] >> 10], 1u);
    __syncthreads();

    // Reserve global range per row: one parallel cursor atomic per non-empty row.
    if (tid < H) {
        unsigned n = s_bin[tid];
        s_gb[tid] = n ? atomicAdd(&cursor[b * H + tid], n) : 0u;
    }
    __syncthreads();

    // Pass B: write votes directly to global row buckets (L2 merges the
    // per-(block,row) consecutive u16 stores).
    unsigned labsh = (unsigned)lab << 10;
    #pragma unroll
    for (int i = 0; i < 32; ++i) {
        unsigned vt = vote[i];
        if (vt != 0xFFFFFFFFu) {
            unsigned py = vt >> 10;
            unsigned rel = atomicAdd(&s_rel[py], 1u);
            unsigned g = s_gb[py] + rel;
            if (g < (unsigned)CAP)
                bucketData[(size_t)(b * H + py) * CAP + g] =
                    (unsigned short)(labsh | (vt & 1023u));
        }
    }

    // Class aggregates (s_ccnt/s_cz final since the first barrier).
    if (tid < C) {
        unsigned c = s_ccnt[tid];
        if (c) {
            atomicAdd(&cnt[b * C + tid], c);
            atomicAdd(&zsum[b * C + tid], s_cz[tid]);
        }
    }
}

__global__ __launch_bounds__(256) void hist_kernel(
    const unsigned short* __restrict__ bucketData,
    const unsigned* __restrict__ cursor,
    unsigned long long* __restrict__ keys,
    int C, int H, int W, int CAP)
{
    extern __shared__ char sm[];
    unsigned* hist = (unsigned*)sm;   // C*W/2 words, u16 pair per word
    unsigned long long* s_wb =
        (unsigned long long*)(sm + (size_t)(C * W / 2) * 4);  // C*4 wave bests

    int tid = threadIdx.x;
    int lane = tid & 63, wave = tid >> 6;
    int py = blockIdx.x;
    int b = blockIdx.y;
    int words = C * W / 2;

    for (int i = tid; i < words; i += 256) hist[i] = 0u;
    __syncthreads();

    int bucket = b * H + py;
    unsigned n = cursor[bucket];
    if (n > (unsigned)CAP) n = (unsigned)CAP;
    const unsigned short* src = bucketData + (size_t)bucket * CAP;
    for (unsigned i = tid; i < n; i += 256) {
        unsigned r = src[i];
        unsigned idx = (r >> 10) * (unsigned)W + (r & 1023u);  // c*W+px
        atomicAdd(&hist[idx >> 1], 1u << ((idx & 1u) * 16));   // packed u16; max <= CAP < 65536
    }
    __syncthreads();

    // Per-class argmax over ALL cells of this row (zero counts included so
    // global tie-break == jnp.argmax: max count, then min flat index).
    unsigned rowbase = (unsigned)py * (unsigned)W;
    for (int c = 0; c < C; ++c) {
        unsigned long long best = 0;
        for (int px = tid; px < W; px += 256) {
            unsigned cv = (hist[(unsigned)(c * W + px) >> 1] >> ((px & 1) * 16)) & 0xFFFFu;
            unsigned long long k = ((unsigned long long)cv << 32)
                                 | (unsigned long long)(0xFFFFFFFFu - (rowbase + px));
            if (k > best) best = k;
        }
        #pragma unroll
        for (int off = 32; off > 0; off >>= 1) {
            unsigned long long o = __shfl_xor(best, off, 64);
            if (o > best) best = o;
        }
        if (lane == 0) s_wb[c * 4 + wave] = best;
    }
    __syncthreads();
    if (tid < C) {
        unsigned long long m = s_wb[tid * 4];
        #pragma unroll
        for (int w2 = 1; w2 < 4; ++w2)
            if (s_wb[tid * 4 + w2] > m) m = s_wb[tid * 4 + w2];
        atomicMax(&keys[b * C + tid], m);
    }
}

__global__ void finalize_kernel(const unsigned long long* __restrict__ keys,
                                const unsigned* __restrict__ cnt,
                                const float* __restrict__ zsum,
                                const float* __restrict__ extents,
                                const float* __restrict__ meta,
                                float* __restrict__ out,
                                int B, int C, int W)
{
    int i = threadIdx.x;
    if (i >= B * C) return;
    int b = i / C, c = i % C;
    unsigned long long k = keys[i];
    unsigned votes = (unsigned)(k >> 32);
    unsigned peak = 0xFFFFFFFFu - (unsigned)(k & 0xFFFFFFFFull);
    float cx = (float)(peak % (unsigned)W);
    float cy = (float)(peak / (unsigned)W);
    float n = (float)cnt[i];
    float depth = zsum[i] / fmaxf(n, 1.0f);
    float fx = meta[b * 9 + 0];
    const float* e = extents + c * 3;
    float diag = sqrtf(e[0] * e[0] + e[1] * e[1] + e[2] * e[2]);
    float half = 0.5f * diag * fx / fmaxf(fabsf(depth), 0.001f);
    float* o = out + (size_t)i * 9;
    o[0] = (float)c;
    o[1] = (float)votes;
    o[2] = cx - half;
    o[3] = cy - half;
    o[4] = cx + half;
    o[5] = cy + half;
    o[6] = cx;
    o[7] = cy;
    o[8] = depth;
}

extern "C" void kernel_launch(void* const* d_in, const int* in_sizes, int n_in,
                              void* d_out, int out_size, void* d_ws, size_t ws_size,
                              hipStream_t stream)
{
    const int* label    = (const int*)d_in[0];
    const float* vertex = (const float*)d_in[1];
    const float* extents= (const float*)d_in[2];
    const float* meta   = (const float*)d_in[3];
    // d_in[4] = gt (unused), d_in[5] = is_train (unused)

    int C = in_sizes[2] / 3;      // extents: C*3
    int B = in_sizes[3] / 9;      // meta: B*9
    int HW = in_sizes[0] / B;     // label: B*H*W
    const int W = 640;
    int H = HW / W;
    int NB = B * H;               // number of row buckets

    // Workspace layout: keys (u64) | cursor (u32) | cnt | zsum | pad | bucketData (u16)
    size_t keysOff = 0;
    size_t curOff  = keysOff + (size_t)B * C * 8;
    size_t cntOff  = curOff + (size_t)NB * 4;
    size_t zsumOff = cntOff + (size_t)B * C * 4;
    size_t zeroEnd = zsumOff + (size_t)B * C * 4;
    size_t dataOff = (zeroEnd + 63) & ~(size_t)63;

    // Adaptive bucket capacity (records are u16). Mean load ~20K/bucket.
    size_t availRec = (ws_size > dataOff) ? (ws_size - dataOff) / ((size_t)NB * 2) : 0;
    int CAP = (int)(availRec > 32768 ? 32768 : availRec);
    CAP &= ~63;

    unsigned long long* keys = (unsigned long long*)((char*)d_ws + keysOff);
    unsigned* cursor         = (unsigned*)((char*)d_ws + curOff);
    unsigned* cnt            = (unsigned*)((char*)d_ws + cntOff);
    float* zsum              = (float*)((char*)d_ws + zsumOff);
    unsigned short* bucketData = (unsigned short*)((char*)d_ws + dataOff);

    hipMemsetAsync(d_ws, 0, zeroEnd, stream);

    dim3 egrid((HW + 511) / 512, B);
    emit_kernel<<<egrid, 512, 0, stream>>>(label, vertex, bucketData, cursor,
                                           cnt, zsum, C, H, W, HW, CAP);

    dim3 hgrid(H, B);
    size_t hsm = (size_t)(C * W / 2) * 4 + (size_t)C * 4 * 8;
    hist_kernel<<<hgrid, 256, hsm, stream>>>(bucketData, cursor, keys, C, H, W, CAP);

    finalize_kernel<<<1, 64, 0, stream>>>(keys, cnt, zsum, extents, meta,
                                          (float*)d_out, B, C, W);
}

// Round 8
// 121.727 us; speedup vs baseline: 1.4684x; 1.0570x over previous
//
#include <hip/hip_runtime.h>

// Hough voting (PoseCNN-style), two-phase binned version, round 8.
// label (B,H,W) i32; vertex (B,3C,H,W) f32; extents (C,3); meta (B,9);
// out (B,C,9) f32. B=2,C=22,H=480,W=640. Assumes H <= 512, C < 32.
//
// r8 change: r4/r5/r6/r7 all floor at ~110-165us with every pipe <25% busy.
// Diagnosis: ~480K device-scope cursor atomics over only 960 addresses =
// ~500 same-address serialized atomics each (~100ns per r2 calibration)
// ~= 50us invisible floor. Fix: 4-way segment each row bucket by
// blockIdx.x&3 -> per-address chain 500 -> ~125 (~12us). hist sums the
// 4 segments. Everything else identical to r7.

#define MAXC 32
#define NSEG 4

__global__ __launch_bounds__(512) void emit_kernel(
    const int* __restrict__ label, const float* __restrict__ vertex,
    unsigned short* __restrict__ bucketData, unsigned* __restrict__ cursor,
    unsigned* __restrict__ cnt, float* __restrict__ zsum,
    int C, int H, int W, int HW, int SEGCAP, int NB)
{
    __shared__ unsigned s_bin[512];   // votes per destination row
    __shared__ unsigned s_rel[512];   // block-local write offset per row
    __shared__ unsigned s_gb[512];    // global base per row (within segment)
    __shared__ unsigned s_ccnt[MAXC];
    __shared__ float s_cz[MAXC];

    int tid = threadIdx.x;
    int b = blockIdx.y;
    int p = blockIdx.x * 512 + tid;
    int seg = blockIdx.x & (NSEG - 1);

    s_bin[tid] = 0u;
    s_rel[tid] = 0u;
    if (tid < MAXC) { s_ccnt[tid] = 0u; s_cz[tid] = 0.0f; }
    __syncthreads();

    int lab = 0;
    unsigned vote[32];   // py<<10 | px, 0xFFFFFFFF = invalid (static idx only)
    bool fg = false;
    if (p < HW) {
        lab = label[(size_t)b * HW + p];
        const float* vb = vertex + ((size_t)(b * 3 * C + 3 * lab)) * HW + p;
        float nx = vb[0];
        float ny = vb[(size_t)HW];
        float z  = vb[2 * (size_t)HW];
        atomicAdd(&s_ccnt[lab], 1u);
        atomicAdd(&s_cz[lab], z);
        if (lab > 0) {
            fg = true;
            // Match XLA f32 exactly: no FMA contraction, IEEE sqrt/div, RNE round.
            float nrm = __fsqrt_rn(__fadd_rn(__fmul_rn(nx, nx), __fmul_rn(ny, ny)));
            float inv = __fdiv_rn(1.0f, __fadd_rn(nrm, 1e-8f));
            float nxn = __fmul_rn(nx, inv);
            float nyn = __fmul_rn(ny, inv);
            float xs = (float)(p % W);
            float ys = (float)(p / W);
            #pragma unroll
            for (int i = 1; i <= 32; ++i) {
                float t = (float)i * 4.0f;
                int px = (int)rintf(__fadd_rn(xs, __fmul_rn(nxn, t)));
                int py = (int)rintf(__fadd_rn(ys, __fmul_rn(nyn, t)));
                vote[i - 1] = (px >= 0 && px < W && py >= 0 && py < H)
                            ? ((unsigned)(py << 10) | (unsigned)px) : 0xFFFFFFFFu;
            }
        }
    }
    if (!fg) {
        #pragma unroll
        for (int i = 0; i < 32; ++i) vote[i] = 0xFFFFFFFFu;
    }

    // Pass A: count votes per destination row.
    #pragma unroll
    for (int i = 0; i < 32; ++i)
        if (vote[i] != 0xFFFFFFFFu) atomicAdd(&s_bin[vote[i] >> 10], 1u);
    __syncthreads();

    // Reserve range in THIS block's segment of each row bucket: one parallel
    // cursor atomic per non-empty row. 4-way segmentation cuts same-address
    // serialization ~4x.
    if (tid < H) {
        unsigned n = s_bin[tid];
        s_gb[tid] = n ? atomicAdd(&cursor[seg * NB + b * H + tid], n) : 0u;
    }
    __syncthreads();

    // Pass B: write votes directly to the segment of the global row bucket.
    unsigned labsh = (unsigned)lab << 10;
    #pragma unroll
    for (int i = 0; i < 32; ++i) {
        unsigned vt = vote[i];
        if (vt != 0xFFFFFFFFu) {
            unsigned py = vt >> 10;
            unsigned rel = atomicAdd(&s_rel[py], 1u);
            unsigned g = s_gb[py] + rel;
            if (g < (unsigned)SEGCAP)
                bucketData[((size_t)(b * H + py) * NSEG + seg) * SEGCAP + g] =
                    (unsigned short)(labsh | (vt & 1023u));
        }
    }

    // Class aggregates (s_ccnt/s_cz final since the first barrier).
    if (tid < C) {
        unsigned c = s_ccnt[tid];
        if (c) {
            atomicAdd(&cnt[b * C + tid], c);
            atomicAdd(&zsum[b * C + tid], s_cz[tid]);
        }
    }
}

__global__ __launch_bounds__(256) void hist_kernel(
    const unsigned short* __restrict__ bucketData,
    const unsigned* __restrict__ cursor,
    unsigned long long* __restrict__ keys,
    int C, int H, int W, int SEGCAP, int NB)
{
    extern __shared__ char sm[];
    unsigned* hist = (unsigned*)sm;   // C*W/2 words, u16 pair per word
    unsigned long long* s_wb =
        (unsigned long long*)(sm + (size_t)(C * W / 2) * 4);  // C*4 wave bests

    int tid = threadIdx.x;
    int lane = tid & 63, wave = tid >> 6;
    int py = blockIdx.x;
    int b = blockIdx.y;
    int words = C * W / 2;

    for (int i = tid; i < words; i += 256) hist[i] = 0u;
    __syncthreads();

    int bucket = b * H + py;
    #pragma unroll
    for (int seg = 0; seg < NSEG; ++seg) {
        unsigned n = cursor[seg * NB + bucket];
        if (n > (unsigned)SEGCAP) n = (unsigned)SEGCAP;
        const unsigned short* src =
            bucketData + ((size_t)bucket * NSEG + seg) * SEGCAP;
        for (unsigned i = tid; i < n; i += 256) {
            unsigned r = src[i];
            unsigned idx = (r >> 10) * (unsigned)W + (r & 1023u);  // c*W+px
            atomicAdd(&hist[idx >> 1], 1u << ((idx & 1u) * 16));   // packed u16
        }
    }
    __syncthreads();

    // Per-class argmax over ALL cells of this row (zero counts included so
    // global tie-break == jnp.argmax: max count, then min flat index).
    unsigned rowbase = (unsigned)py * (unsigned)W;
    for (int c = 0; c < C; ++c) {
        unsigned long long best = 0;
        for (int px = tid; px < W; px += 256) {
            unsigned cv = (hist[(unsigned)(c * W + px) >> 1] >> ((px & 1) * 16)) & 0xFFFFu;
            unsigned long long k = ((unsigned long long)cv << 32)
                                 | (unsigned long long)(0xFFFFFFFFu - (rowbase + px));
            if (k > best) best = k;
        }
        #pragma unroll
        for (int off = 32; off > 0; off >>= 1) {
            unsigned long long o = __shfl_xor(best, off, 64);
            if (o > best) best = o;
        }
        if (lane == 0) s_wb[c * 4 + wave] = best;
    }
    __syncthreads();
    if (tid < C) {
        unsigned long long m = s_wb[tid * 4];
        #pragma unroll
        for (int w2 = 1; w2 < 4; ++w2)
            if (s_wb[tid * 4 + w2] > m) m = s_wb[tid * 4 + w2];
        atomicMax(&keys[b * C + tid], m);
    }
}

__global__ void finalize_kernel(const unsigned long long* __restrict__ keys,
                                const unsigned* __restrict__ cnt,
                                const float* __restrict__ zsum,
                                const float* __restrict__ extents,
                                const float* __restrict__ meta,
                                float* __restrict__ out,
                                int B, int C, int W)
{
    int i = threadIdx.x;
    if (i >= B * C) return;
    int b = i / C, c = i % C;
    unsigned long long k = keys[i];
    unsigned votes = (unsigned)(k >> 32);
    unsigned peak = 0xFFFFFFFFu - (unsigned)(k & 0xFFFFFFFFull);
    float cx = (float)(peak % (unsigned)W);
    float cy = (float)(peak / (unsigned)W);
    float n = (float)cnt[i];
    float depth = zsum[i] / fmaxf(n, 1.0f);
    float fx = meta[b * 9 + 0];
    const float* e = extents + c * 3;
    float diag = sqrtf(e[0] * e[0] + e[1] * e[1] + e[2] * e[2]);
    float half = 0.5f * diag * fx / fmaxf(fabsf(depth), 0.001f);
    float* o = out + (size_t)i * 9;
    o[0] = (float)c;
    o[1] = (float)votes;
    o[2] = cx - half;
    o[3] = cy - half;
    o[4] = cx + half;
    o[5] = cy + half;
    o[6] = cx;
    o[7] = cy;
    o[8] = depth;
}

extern "C" void kernel_launch(void* const* d_in, const int* in_sizes, int n_in,
                              void* d_out, int out_size, void* d_ws, size_t ws_size,
                              hipStream_t stream)
{
    const int* label    = (const int*)d_in[0];
    const float* vertex = (const float*)d_in[1];
    const float* extents= (const float*)d_in[2];
    const float* meta   = (const float*)d_in[3];
    // d_in[4] = gt (unused), d_in[5] = is_train (unused)

    int C = in_sizes[2] / 3;      // extents: C*3
    int B = in_sizes[3] / 9;      // meta: B*9
    int HW = in_sizes[0] / B;     // label: B*H*W
    const int W = 640;
    int H = HW / W;
    int NB = B * H;               // number of row buckets

    // Workspace: keys (u64) | cursor (u32 x NSEG*NB) | cnt | zsum | pad | bucketData
    size_t keysOff = 0;
    size_t curOff  = keysOff + (size_t)B * C * 8;
    size_t cntOff  = curOff + (size_t)NSEG * NB * 4;
    size_t zsumOff = cntOff + (size_t)B * C * 4;
    size_t zeroEnd = zsumOff + (size_t)B * C * 4;
    size_t dataOff = (zeroEnd + 63) & ~(size_t)63;

    // Adaptive per-segment capacity (records are u16). Mean load ~20K/bucket
    // -> ~5.1K/segment.
    size_t availRec = (ws_size > dataOff) ? (ws_size - dataOff) / ((size_t)NB * NSEG * 2) : 0;
    int SEGCAP = (int)(availRec > 8192 ? 8192 : availRec);
    SEGCAP &= ~63;

    unsigned long long* keys = (unsigned long long*)((char*)d_ws + keysOff);
    unsigned* cursor         = (unsigned*)((char*)d_ws + curOff);
    unsigned* cnt            = (unsigned*)((char*)d_ws + cntOff);
    float* zsum              = (float*)((char*)d_ws + zsumOff);
    unsigned short* bucketData = (unsigned short*)((char*)d_ws + dataOff);

    hipMemsetAsync(d_ws, 0, zeroEnd, stream);

    dim3 egrid((HW + 511) / 512, B);
    emit_kernel<<<egrid, 512, 0, stream>>>(label, vertex, bucketData, cursor,
                                           cnt, zsum, C, H, W, HW, SEGCAP, NB);

    dim3 hgrid(H, B);
    size_t hsm = (size_t)(C * W / 2) * 4 + (size_t)C * 4 * 8;
    hist_kernel<<<hgrid, 256, hsm, stream>>>(bucketData, cursor, keys, C, H, W, SEGCAP, NB);

    finalize_kernel<<<1, 64, 0, stream>>>(keys, cnt, zsum, extents, meta,
                                          (float*)d_out, B, C, W);
}